// Round 1
// 905.730 us; speedup vs baseline: 1.3542x; 1.3542x over previous
//
#include <hip/hip_runtime.h>
#include <math.h>

#define N_NODES 100000
#define E_EDGES 1600000
#define S_SNAP  4
#define D_IN    128
#define H_DIM   256
#define P_POST  10000
#define N4 (S_SNAP * N_NODES)               // 400000
#define E4 (S_SNAP * E_EDGES)               // 6400000

// ---- counting-sort graph prep (replaces hist4/scans/fill4) ----
#define NBKT 128                             // coarse dst buckets per snapshot
#define BW_BKT 782                           // 128*782 = 100096 >= N_NODES
#define CHK 4096                             // edges per partition block
#define KPT (CHK / 256)                      // 16 edges per thread
#define NCHK ((E_EDGES + CHK - 1) / CHK)     // 391 chunks per snapshot
#define NPB (S_SNAP * NBKT)                  // 512 (snapshot,bucket) units

typedef __attribute__((ext_vector_type(8))) short bf16x8;   // MFMA A/B frag (4 VGPRs)
typedef __attribute__((ext_vector_type(4))) float f32x4;    // MFMA C/D frag

// ---------- bf16 helpers ----------
__device__ __forceinline__ float bf2f(unsigned short u) {
    union { unsigned int i; float f; } v; v.i = ((unsigned int)u) << 16; return v.f;
}
__device__ __forceinline__ unsigned short f2bf(float f) {
    union { float f; unsigned int i; } v; v.f = f;
    unsigned int lsb = (v.i >> 16) & 1u;
    v.i += 0x7fffu + lsb;                 // round-nearest-even
    return (unsigned short)(v.i >> 16);
}

// ---------------- utility ----------------
__global__ void zero32_kernel(unsigned int* __restrict__ p, int n) {
    int i = blockIdx.x * blockDim.x + threadIdx.x;
    if (i < n) p[i] = 0u;
}

// ---- pass 1a: per-chunk LDS histogram over 128 coarse buckets.
//      Global atomics: NBKT per block (200K total vs 6.4M in old hist4).
__global__ __launch_bounds__(256) void part_count_kernel(const int* __restrict__ ei,
        int* __restrict__ gcnt, int* __restrict__ cbase) {
    __shared__ int cnt[NBKT];
    int bx = blockIdx.x;
    int s = bx / NCHK, c = bx - s * NCHK;
    int t = threadIdx.x;
    if (t < NBKT) cnt[t] = 0;
    __syncthreads();
    const int* dstp = ei + (size_t)s * 2 * E_EDGES + E_EDGES;
    int base = c * CHK + t;
    #pragma unroll
    for (int k = 0; k < KPT; ++k) {
        int j = base + k * 256;
        if (j < E_EDGES) atomicAdd(&cnt[dstp[j] / BW_BKT], 1);   // LDS atomic
    }
    __syncthreads();
    if (t < NBKT) {
        int v = cnt[t];
        cbase[(size_t)bx * NBKT + t] = atomicAdd(&gcnt[s * NBKT + t], v);
    }
}

// ---- tiny scan: bucket totals -> global bucket offsets (s-major, matches rowptr order)
__global__ __launch_bounds__(512) void scan_gcnt_kernel(const int* __restrict__ gcnt,
        int* __restrict__ boffb, int* __restrict__ rowptr4) {
    __shared__ int sh[512];
    int t = threadIdx.x;
    int v = gcnt[t];                           // exactly NPB=512 entries
    sh[t] = v;
    __syncthreads();
    for (int off = 1; off < 512; off <<= 1) {
        int u = (t >= off) ? sh[t - off] : 0;
        __syncthreads();
        sh[t] += u;
        __syncthreads();
    }
    boffb[t] = sh[t] - v;                      // exclusive
    if (t == 0) rowptr4[N4] = E4;
}

// ---- pass 1b: partition edges into bucket-contiguous packed records
//      (src | dstLocal<<17).  LDS reorder so global writes are coalesced runs.
__global__ __launch_bounds__(256) void part_scatter_kernel(const int* __restrict__ ei,
        const int* __restrict__ boffb, const int* __restrict__ cbase,
        unsigned int* __restrict__ packed) {
    __shared__ int cnt[NBKT];
    __shared__ int sco[NBKT];
    __shared__ int lofs[NBKT + 1];
    __shared__ int cb2[NBKT];
    __shared__ unsigned int lbuf[CHK];         // 16 KB staging
    int bx = blockIdx.x;
    int s = bx / NCHK, c = bx - s * NCHK;
    int t = threadIdx.x;
    if (t < NBKT) cnt[t] = 0;
    __syncthreads();
    const int* srcp = ei + (size_t)s * 2 * E_EDGES;
    const int* dstp = srcp + E_EDGES;
    int base = c * CHK + t;
    unsigned int pv[KPT];
    int prb[KPT];                              // (bucket<<13) | rank  (rank < 4096)
    #pragma unroll
    for (int k = 0; k < KPT; ++k) {
        int j = base + k * 256;
        prb[k] = -1;
        if (j < E_EDGES) {
            int d = dstp[j];
            int b = d / BW_BKT;
            int dl = d - b * BW_BKT;           // < 782 -> 10 bits; src < 2^17
            pv[k] = (unsigned int)srcp[j] | ((unsigned int)dl << 17);
            int r = atomicAdd(&cnt[b], 1);     // LDS atomic, unique rank in (chunk,bucket)
            prb[k] = (b << 13) | r;
        }
    }
    __syncthreads();
    if (t < NBKT) sco[t] = cnt[t];
    __syncthreads();
    for (int off = 1; off < NBKT; off <<= 1) { // exclusive scan over 128 counters
        int u = (t < NBKT && t >= off) ? sco[t - off] : 0;
        __syncthreads();
        if (t < NBKT) sco[t] += u;
        __syncthreads();
    }
    if (t < NBKT) {
        int ex = sco[t] - cnt[t];
        lofs[t] = ex;
        if (t == NBKT - 1) lofs[NBKT] = sco[t];
        // out position for lbuf[i] in bucket b is cb2[b] + i
        cb2[t] = boffb[s * NBKT + t] + cbase[(size_t)bx * NBKT + t] - ex;
    }
    __syncthreads();
    #pragma unroll
    for (int k = 0; k < KPT; ++k) {
        if (prb[k] >= 0) lbuf[lofs[prb[k] >> 13] + (prb[k] & 0x1FFF)] = pv[k];
    }
    __syncthreads();
    int tot = lofs[NBKT];
    for (int i = t; i < tot; i += 256) {       // consecutive i -> coalesced bucket runs
        unsigned int v = lbuf[i];
        int lo = 0, hi = NBKT;                 // invariant: lofs[lo] <= i < lofs[hi]
        while (hi - lo > 1) {
            int mid = (lo + hi) >> 1;
            if (lofs[mid] <= i) lo = mid; else hi = mid;
        }
        packed[cb2[lo] + i] = v;
    }
}

// ---- pass 2: per-(snapshot,bucket) CSR build entirely with LDS atomics.
//      deg -> rowptr4/dinv4 (LDS scan), then cursor placement of csrsrc4.
__global__ __launch_bounds__(1024) void bucket_csr_kernel(const unsigned int* __restrict__ packed,
        const int* __restrict__ gcnt, const int* __restrict__ boffb,
        int* __restrict__ rowptr4, float* __restrict__ dinv4, int* __restrict__ csrsrc4) {
    __shared__ int deg[BW_BKT];                // histogram, then cursor
    __shared__ int sc[1024];
    int bx = blockIdx.x;                       // s*NBKT + b
    int s = bx >> 7, b = bx & (NBKT - 1);
    int t = threadIdx.x;
    int ebase = boffb[bx];
    int ecnt = gcnt[bx];
    for (int i = t; i < BW_BKT; i += 1024) deg[i] = 0;
    __syncthreads();
    const unsigned int* pk = packed + ebase;
    for (int i = t; i < ecnt; i += 1024) atomicAdd(&deg[pk[i] >> 17], 1);  // LDS atomic
    __syncthreads();
    int d0 = (t < BW_BKT) ? deg[t] : 0;
    sc[t] = d0;
    __syncthreads();
    for (int off = 1; off < 1024; off <<= 1) { // block scan over 1024 (>=782)
        int u = (t >= off) ? sc[t - off] : 0;
        __syncthreads();
        sc[t] += u;
        __syncthreads();
    }
    int ex = sc[t] - d0;                       // exclusive within bucket
    int g = b * BW_BKT + t;
    if (t < BW_BKT && g < N_NODES) {
        rowptr4[s * N_NODES + g] = ebase + ex;
        dinv4[s * N_NODES + g] = rsqrtf((float)(d0 + 1));   // +1 self-loop
    }
    __syncthreads();
    if (t < BW_BKT) deg[t] = ex;               // becomes cursor
    __syncthreads();
    for (int i = t; i < ecnt; i += 1024) {
        unsigned int p = pk[i];
        int r = atomicAdd(&deg[p >> 17], 1);   // LDS atomic, unique slot per dst
        csrsrc4[ebase + r] = (int)(p & 0x1FFFFu);
    }
}

// ------- MFMA GEMM (once per call): xw1 = x @ W1, bf16 out -------
// Layouts (HW-verified r8): A[m=lane&15][k=quad*8+j]; B[k][n=lane&15]; C/D col=lane&15,row=quad*4+reg
__global__ __launch_bounds__(256) void gemm_xw1_mfma(const float* __restrict__ A,
        const float* __restrict__ B, unsigned short* __restrict__ C, int M) {
    __shared__ unsigned short As[64][136];   // [m][k], +8 pad
    __shared__ unsigned short Bs[64][136];   // [n][k]
    int tid = threadIdx.x;
    int m0 = blockIdx.x * 64, n0 = blockIdx.y * 64;
    {
        int row = tid >> 2, c0 = (tid & 3) * 32;
        int gm = m0 + row;
        #pragma unroll
        for (int i = 0; i < 8; ++i) {
            float4 v = make_float4(0.f, 0.f, 0.f, 0.f);
            if (gm < M) v = *(const float4*)(A + (size_t)gm * D_IN + c0 + i * 4);
            As[row][c0 + i * 4 + 0] = f2bf(v.x);
            As[row][c0 + i * 4 + 1] = f2bf(v.y);
            As[row][c0 + i * 4 + 2] = f2bf(v.z);
            As[row][c0 + i * 4 + 3] = f2bf(v.w);
        }
    }
    {
        int k = tid >> 1, nb = (tid & 1) * 32;
        #pragma unroll
        for (int i = 0; i < 8; ++i) {
            float4 v = *(const float4*)(B + (size_t)k * H_DIM + n0 + nb + i * 4);
            Bs[nb + i * 4 + 0][k] = f2bf(v.x);
            Bs[nb + i * 4 + 1][k] = f2bf(v.y);
            Bs[nb + i * 4 + 2][k] = f2bf(v.z);
            Bs[nb + i * 4 + 3][k] = f2bf(v.w);
        }
    }
    __syncthreads();
    int w = tid >> 6, l = tid & 63;
    int q = l >> 4, mrow = l & 15;
    f32x4 acc[4] = {{0.f,0.f,0.f,0.f},{0.f,0.f,0.f,0.f},{0.f,0.f,0.f,0.f},{0.f,0.f,0.f,0.f}};
    #pragma unroll
    for (int kk = 0; kk < 4; ++kk) {
        bf16x8 a = *(const bf16x8*)&As[16 * w + mrow][kk * 32 + q * 8];
        #pragma unroll
        for (int ct = 0; ct < 4; ++ct) {
            bf16x8 b = *(const bf16x8*)&Bs[ct * 16 + mrow][kk * 32 + q * 8];
            acc[ct] = __builtin_amdgcn_mfma_f32_16x16x32_bf16(a, b, acc[ct], 0, 0, 0);
        }
    }
    #pragma unroll
    for (int ct = 0; ct < 4; ++ct) {
        int col = n0 + ct * 16 + mrow;
        #pragma unroll
        for (int i = 0; i < 4; ++i) {
            int m = m0 + 16 * w + q * 4 + i;
            if (m < M) C[(size_t)m * H_DIM + col] = f2bf(acc[ct][i]);
        }
    }
}

// ------- SpMM layer 0 (fused bias+relu), 4-way edge unroll (r7/r9-proven: VGPR 20) -------
__global__ __launch_bounds__(256) void spmm_l0_kernel(const unsigned short* __restrict__ xw1,
        const float* __restrict__ dinv4, const int* __restrict__ rowptr4,
        const int* __restrict__ csrsrc4, const float* __restrict__ b1,
        unsigned short* __restrict__ h, int soff) {
    int r = (blockIdx.x << 2) + (threadIdx.x >> 6);
    int lane = threadIdx.x & 63;
    int rg = soff + r;
    int e0 = rowptr4[rg], e1 = rowptr4[rg + 1];
    float di = dinv4[rg];
    float4 acc = make_float4(0.f, 0.f, 0.f, 0.f);
    const ushort4* tp = (const ushort4*)xw1;
    const float* dv = dinv4 + soff;
    int e = e0;
    for (; e + 4 <= e1; e += 4) {
        int s0 = csrsrc4[e], s1 = csrsrc4[e + 1], s2 = csrsrc4[e + 2], s3 = csrsrc4[e + 3];
        float w0 = dv[s0] * di, w1 = dv[s1] * di, w2 = dv[s2] * di, w3 = dv[s3] * di;
        ushort4 u0 = tp[(size_t)s0 * 64 + lane];
        ushort4 u1 = tp[(size_t)s1 * 64 + lane];
        ushort4 u2 = tp[(size_t)s2 * 64 + lane];
        ushort4 u3 = tp[(size_t)s3 * 64 + lane];
        acc.x = fmaf(bf2f(u0.x), w0, acc.x); acc.y = fmaf(bf2f(u0.y), w0, acc.y);
        acc.z = fmaf(bf2f(u0.z), w0, acc.z); acc.w = fmaf(bf2f(u0.w), w0, acc.w);
        acc.x = fmaf(bf2f(u1.x), w1, acc.x); acc.y = fmaf(bf2f(u1.y), w1, acc.y);
        acc.z = fmaf(bf2f(u1.z), w1, acc.z); acc.w = fmaf(bf2f(u1.w), w1, acc.w);
        acc.x = fmaf(bf2f(u2.x), w2, acc.x); acc.y = fmaf(bf2f(u2.y), w2, acc.y);
        acc.z = fmaf(bf2f(u2.z), w2, acc.z); acc.w = fmaf(bf2f(u2.w), w2, acc.w);
        acc.x = fmaf(bf2f(u3.x), w3, acc.x); acc.y = fmaf(bf2f(u3.y), w3, acc.y);
        acc.z = fmaf(bf2f(u3.z), w3, acc.z); acc.w = fmaf(bf2f(u3.w), w3, acc.w);
    }
    for (; e < e1; ++e) {
        int s = csrsrc4[e];
        float wv = dv[s] * di;
        ushort4 u = tp[(size_t)s * 64 + lane];
        acc.x = fmaf(bf2f(u.x), wv, acc.x); acc.y = fmaf(bf2f(u.y), wv, acc.y);
        acc.z = fmaf(bf2f(u.z), wv, acc.z); acc.w = fmaf(bf2f(u.w), wv, acc.w);
    }
    ushort4 us = tp[(size_t)r * 64 + lane];
    float wd = di * di;
    float4 bb = ((const float4*)b1)[lane];
    ushort4 o;
    o.x = f2bf(fmaxf(fmaf(bf2f(us.x), wd, acc.x) + bb.x, 0.f));
    o.y = f2bf(fmaxf(fmaf(bf2f(us.y), wd, acc.y) + bb.y, 0.f));
    o.z = f2bf(fmaxf(fmaf(bf2f(us.z), wd, acc.z) + bb.z, 0.f));
    o.w = f2bf(fmaxf(fmaf(bf2f(us.w), wd, acc.w) + bb.w, 0.f));
    ((ushort4*)h)[(size_t)r * 64 + lane] = o;
}

// --- SpMM layer 1 (post rows), accumulating across snapshots:
//     t1acc[p] (+)= (Ahat_s @ h_s)[post[p]],  hacc[p] (+)= h_s[post[p]]  (self row is free)
__global__ __launch_bounds__(256) void spmm_h_post_kernel(const unsigned short* __restrict__ h,
        const float* __restrict__ dinv4, const int* __restrict__ rowptr4,
        const int* __restrict__ csrsrc4, const int* __restrict__ post,
        float* __restrict__ t1acc, float* __restrict__ hacc, int soff, int first) {
    int p = (blockIdx.x << 2) + (threadIdx.x >> 6);
    int lane = threadIdx.x & 63;
    int r = post[p];
    int rg = soff + r;
    int e0 = rowptr4[rg], e1 = rowptr4[rg + 1];
    float di = dinv4[rg];
    float4 acc = make_float4(0.f, 0.f, 0.f, 0.f);
    const ushort4* hp = (const ushort4*)h;
    const float* dv = dinv4 + soff;
    int e = e0;
    for (; e + 4 <= e1; e += 4) {
        int s0 = csrsrc4[e], s1 = csrsrc4[e + 1], s2 = csrsrc4[e + 2], s3 = csrsrc4[e + 3];
        float w0 = dv[s0] * di, w1 = dv[s1] * di, w2 = dv[s2] * di, w3 = dv[s3] * di;
        ushort4 u0 = hp[(size_t)s0 * 64 + lane];
        ushort4 u1 = hp[(size_t)s1 * 64 + lane];
        ushort4 u2 = hp[(size_t)s2 * 64 + lane];
        ushort4 u3 = hp[(size_t)s3 * 64 + lane];
        acc.x = fmaf(bf2f(u0.x), w0, acc.x); acc.y = fmaf(bf2f(u0.y), w0, acc.y);
        acc.z = fmaf(bf2f(u0.z), w0, acc.z); acc.w = fmaf(bf2f(u0.w), w0, acc.w);
        acc.x = fmaf(bf2f(u1.x), w1, acc.x); acc.y = fmaf(bf2f(u1.y), w1, acc.y);
        acc.z = fmaf(bf2f(u1.z), w1, acc.z); acc.w = fmaf(bf2f(u1.w), w1, acc.w);
        acc.x = fmaf(bf2f(u2.x), w2, acc.x); acc.y = fmaf(bf2f(u2.y), w2, acc.y);
        acc.z = fmaf(bf2f(u2.z), w2, acc.z); acc.w = fmaf(bf2f(u2.w), w2, acc.w);
        acc.x = fmaf(bf2f(u3.x), w3, acc.x); acc.y = fmaf(bf2f(u3.y), w3, acc.y);
        acc.z = fmaf(bf2f(u3.z), w3, acc.z); acc.w = fmaf(bf2f(u3.w), w3, acc.w);
    }
    for (; e < e1; ++e) {
        int s = csrsrc4[e];
        float wv = dv[s] * di;
        ushort4 u = hp[(size_t)s * 64 + lane];
        acc.x = fmaf(bf2f(u.x), wv, acc.x); acc.y = fmaf(bf2f(u.y), wv, acc.y);
        acc.z = fmaf(bf2f(u.z), wv, acc.z); acc.w = fmaf(bf2f(u.w), wv, acc.w);
    }
    ushort4 u = hp[(size_t)r * 64 + lane];        // self row = h_s[post[p]]
    float hx = bf2f(u.x), hy = bf2f(u.y), hz = bf2f(u.z), hw = bf2f(u.w);
    float wd = di * di;
    acc.x = fmaf(hx, wd, acc.x);
    acc.y = fmaf(hy, wd, acc.y);
    acc.z = fmaf(hz, wd, acc.z);
    acc.w = fmaf(hw, wd, acc.w);
    size_t idx = (size_t)p * 64 + lane;
    float4 hv = make_float4(hx, hy, hz, hw);
    if (first) {
        ((float4*)t1acc)[idx] = acc;
        ((float4*)hacc)[idx] = hv;
    } else {
        float4 a = ((float4*)t1acc)[idx];
        a.x += acc.x; a.y += acc.y; a.z += acc.z; a.w += acc.w;
        ((float4*)t1acc)[idx] = a;
        float4 b = ((float4*)hacc)[idx];
        b.x += hv.x; b.y += hv.y; b.z += hv.z; b.w += hv.w;
        ((float4*)hacc)[idx] = b;
    }
}

// ------- MFMA GEMM layer 1 (ONCE): accP = t1acc @ W2 + 4*b2 + hacc -------
__global__ __launch_bounds__(256) void gemm_l1_mfma(const float* __restrict__ A,
        const float* __restrict__ B, const float* __restrict__ b2,
        const float* __restrict__ hacc, float* __restrict__ accP, int M) {
    __shared__ unsigned short As[64][136];
    __shared__ unsigned short Bs[64][136];
    int tid = threadIdx.x;
    int m0 = blockIdx.x * 64, n0 = blockIdx.y * 64;
    int w = tid >> 6, l = tid & 63;
    int q = l >> 4, mrow = l & 15;
    f32x4 acc[4] = {{0.f,0.f,0.f,0.f},{0.f,0.f,0.f,0.f},{0.f,0.f,0.f,0.f},{0.f,0.f,0.f,0.f}};
    for (int kk = 0; kk < 256; kk += 128) {
        __syncthreads();
        {
            int row = tid >> 2, c0 = (tid & 3) * 32;
            int gm = m0 + row;
            #pragma unroll
            for (int i = 0; i < 8; ++i) {
                float4 v = make_float4(0.f, 0.f, 0.f, 0.f);
                if (gm < M) v = *(const float4*)(A + (size_t)gm * 256 + kk + c0 + i * 4);
                As[row][c0 + i * 4 + 0] = f2bf(v.x);
                As[row][c0 + i * 4 + 1] = f2bf(v.y);
                As[row][c0 + i * 4 + 2] = f2bf(v.z);
                As[row][c0 + i * 4 + 3] = f2bf(v.w);
            }
        }
        {
            int k = tid >> 1, nb = (tid & 1) * 32;
            #pragma unroll
            for (int i = 0; i < 8; ++i) {
                float4 v = *(const float4*)(B + (size_t)(kk + k) * H_DIM + n0 + nb + i * 4);
                Bs[nb + i * 4 + 0][k] = f2bf(v.x);
                Bs[nb + i * 4 + 1][k] = f2bf(v.y);
                Bs[nb + i * 4 + 2][k] = f2bf(v.z);
                Bs[nb + i * 4 + 3][k] = f2bf(v.w);
            }
        }
        __syncthreads();
        #pragma unroll
        for (int ks = 0; ks < 4; ++ks) {
            bf16x8 a = *(const bf16x8*)&As[16 * w + mrow][ks * 32 + q * 8];
            #pragma unroll
            for (int ct = 0; ct < 4; ++ct) {
                bf16x8 b = *(const bf16x8*)&Bs[ct * 16 + mrow][ks * 32 + q * 8];
                acc[ct] = __builtin_amdgcn_mfma_f32_16x16x32_bf16(a, b, acc[ct], 0, 0, 0);
            }
        }
    }
    #pragma unroll
    for (int ct = 0; ct < 4; ++ct) {
        int col = n0 + ct * 16 + mrow;
        float bias = 4.0f * b2[col];
        #pragma unroll
        for (int i = 0; i < 4; ++i) {
            int m = m0 + 16 * w + q * 4 + i;
            if (m < M) {
                accP[(size_t)m * 256 + col] =
                    acc[ct][i] + bias + hacc[(size_t)m * 256 + col];
            }
        }
    }
}

// ---------------- classifier ----------------
__global__ __launch_bounds__(128) void classifier_kernel(const float* __restrict__ accP,
        const float* __restrict__ Wc1, const float* __restrict__ bc1,
        const float* __restrict__ Wc2, const float* __restrict__ bc2,
        float* __restrict__ out) {
    __shared__ float arow[8][256];
    __shared__ float red[2][8];
    int p0 = blockIdx.x << 3;
    int tid = threadIdx.x;
    for (int idx = tid; idx < 8 * 256; idx += 128) {
        int pl = idx >> 8, k = idx & 255;
        arow[pl][k] = 0.25f * accP[(size_t)(p0 + pl) * 256 + k];
    }
    __syncthreads();
    float s[8];
    float b = bc1[tid];
    #pragma unroll
    for (int pl = 0; pl < 8; ++pl) s[pl] = b;
    for (int k = 0; k < 256; ++k) {
        float wv = Wc1[k * 128 + tid];
        #pragma unroll
        for (int pl = 0; pl < 8; ++pl) s[pl] = fmaf(arow[pl][k], wv, s[pl]);
    }
    float wc2 = Wc2[tid];
    float part[8];
    #pragma unroll
    for (int pl = 0; pl < 8; ++pl) part[pl] = fmaxf(s[pl], 0.f) * wc2;
    #pragma unroll
    for (int off = 32; off > 0; off >>= 1)
        #pragma unroll
        for (int pl = 0; pl < 8; ++pl) part[pl] += __shfl_down(part[pl], off, 64);
    int wave = tid >> 6, lane = tid & 63;
    if (lane == 0) {
        #pragma unroll
        for (int pl = 0; pl < 8; ++pl) red[wave][pl] = part[pl];
    }
    __syncthreads();
    if (tid < 8) {
        float logit = red[0][tid] + red[1][tid] + bc2[0];
        out[p0 + tid] = 1.f / (1.f + expf(-logit));
    }
}

extern "C" void kernel_launch(void* const* d_in, const int* in_sizes, int n_in,
                              void* d_out, int out_size, void* d_ws, size_t ws_size,
                              hipStream_t stream) {
    const float* x   = (const float*)d_in[0];
    const int*   ei  = (const int*)d_in[1];
    const int*   post= (const int*)d_in[2];
    const float* W1  = (const float*)d_in[3];
    const float* b1  = (const float*)d_in[4];
    const float* W2  = (const float*)d_in[5];
    const float* b2  = (const float*)d_in[6];
    const float* Wc1 = (const float*)d_in[7];
    const float* bc1 = (const float*)d_in[8];
    const float* Wc2 = (const float*)d_in[9];
    const float* bc2 = (const float*)d_in[10];
    float* out = (float*)d_out;

    char* w = (char*)d_ws;
    size_t off = 0;
#define WS_ALLOC(type, name, count) \
    type* name = (type*)(w + off); \
    off += (((size_t)(count) * sizeof(type)) + 255) & ~(size_t)255;
    WS_ALLOC(unsigned short, xw1,     (size_t)N_NODES * H_DIM)   // 51.2 MB (accP aliases)
    WS_ALLOC(unsigned short, hbuf,    (size_t)N_NODES * H_DIM)   // 51.2 MB (packed aliases)
    WS_ALLOC(float,          t1acc,   (size_t)P_POST * H_DIM)    // 10.24 MB
    WS_ALLOC(float,          hacc,    (size_t)P_POST * H_DIM)    // 10.24 MB
    WS_ALLOC(float,          dinv4,   N4)                        // 1.6 MB
    WS_ALLOC(int,            rowptr4, N4 + 4)                    // 1.6 MB
    WS_ALLOC(int,            csrsrc4, E4)                        // 25.6 MB
    WS_ALLOC(int,            cbase,   (size_t)S_SNAP * NCHK * NBKT)  // 0.8 MB
    WS_ALLOC(int,            gcnt,    NPB)
    WS_ALLOC(int,            boffb,   NPB)
#undef WS_ALLOC
    // packed[E4] u32 (25.6 MB) aliases hbuf: dead before spmm_l0 writes h
    // accP [P,256] fp32 (10.24 MB) aliases xw1: xw1 dead after last spmm_l0
    unsigned int* packed = (unsigned int*)hbuf;
    float* accP = (float*)xw1;                       // total ws ~152 MB
    (void)ws_size; (void)in_sizes; (void)n_in; (void)out_size;

    // ---- counting-sort graph prep: no per-edge device atomics ----
    zero32_kernel<<<(NPB + 255) / 256, 256, 0, stream>>>((unsigned int*)gcnt, NPB);
    part_count_kernel<<<S_SNAP * NCHK, 256, 0, stream>>>(ei, gcnt, cbase);
    scan_gcnt_kernel<<<1, 512, 0, stream>>>(gcnt, boffb, rowptr4);
    part_scatter_kernel<<<S_SNAP * NCHK, 256, 0, stream>>>(ei, boffb, cbase, packed);
    bucket_csr_kernel<<<NPB, 1024, 0, stream>>>(packed, gcnt, boffb, rowptr4, dinv4, csrsrc4);

    // xw1 = x @ W1 once per call (snapshot-invariant) — bf16 MFMA
    dim3 gg((N_NODES + 63) / 64, H_DIM / 64);
    gemm_xw1_mfma<<<gg, 256, 0, stream>>>(x, W1, xw1, N_NODES);

    for (int s = 0; s < S_SNAP; ++s) {
        int soff = s * N_NODES;
        // h = relu(Ahat @ xw1 + b1)   [N,256] bf16   (overwrites packed region — dead)
        spmm_l0_kernel<<<N_NODES / 4, 256, 0, stream>>>(xw1, dinv4, rowptr4, csrsrc4,
                                                        b1, hbuf, soff);
        // t1acc (+)= (Ahat @ h)[post];  hacc (+)= h[post]
        spmm_h_post_kernel<<<P_POST / 4, 256, 0, stream>>>(hbuf, dinv4, rowptr4, csrsrc4,
                                                           post, t1acc, hacc, soff, s == 0);
    }
    // accP = t1acc @ W2 + 4*b2 + hacc   — single bf16 MFMA GEMM (W2 snapshot-invariant)
    dim3 g1((P_POST + 63) / 64, H_DIM / 64);
    gemm_l1_mfma<<<g1, 256, 0, stream>>>(t1acc, W2, b2, hacc, accP, P_POST);

    classifier_kernel<<<P_POST / 8, 128, 0, stream>>>(accP, Wc1, bc1, Wc2, bc2, out);
}

// Round 2
// 875.585 us; speedup vs baseline: 1.4009x; 1.0344x over previous
//
#include <hip/hip_runtime.h>
#include <math.h>

#define N_NODES 100000
#define E_EDGES 1600000
#define S_SNAP  4
#define D_IN    128
#define H_DIM   256
#define P_POST  10000
#define N4 (S_SNAP * N_NODES)               // 400000
#define E4 (S_SNAP * E_EDGES)               // 6400000

// ---- counting-sort graph prep ----
#define NBKT 128                             // coarse dst buckets per snapshot
#define BW_BKT 782                           // 128*782 = 100096 >= N_NODES
#define CHK 4096                             // edges per partition block
#define KPT (CHK / 256)                      // 16 edges per thread
#define NCHK ((E_EDGES + CHK - 1) / CHK)     // 391 chunks per snapshot
#define NPB (S_SNAP * NBKT)                  // 512 (snapshot,bucket) units

typedef __attribute__((ext_vector_type(8))) short bf16x8;   // MFMA A/B frag (4 VGPRs)
typedef __attribute__((ext_vector_type(4))) float f32x4;    // MFMA C/D frag

// ---------- bf16 helpers ----------
__device__ __forceinline__ float bf2f(unsigned short u) {
    union { unsigned int i; float f; } v; v.i = ((unsigned int)u) << 16; return v.f;
}
__device__ __forceinline__ unsigned short f2bf(float f) {
    union { float f; unsigned int i; } v; v.f = f;
    unsigned int lsb = (v.i >> 16) & 1u;
    v.i += 0x7fffu + lsb;                 // round-nearest-even
    return (unsigned short)(v.i >> 16);
}

// ---------------- utility ----------------
__global__ void zero32_kernel(unsigned int* __restrict__ p, int n) {
    int i = blockIdx.x * blockDim.x + threadIdx.x;
    if (i < n) p[i] = 0u;
}

// ---- cast X to bf16 once: gather table for layer-0 aggregation (256 B rows) ----
__global__ __launch_bounds__(256) void castx_kernel(const float* __restrict__ x,
        unsigned short* __restrict__ xb) {
    int i = blockIdx.x * 256 + threadIdx.x;      // over N*D/4 = 3.2M float4 groups
    float4 v = ((const float4*)x)[i];
    ushort4 o;
    o.x = f2bf(v.x); o.y = f2bf(v.y); o.z = f2bf(v.z); o.w = f2bf(v.w);
    ((ushort4*)xb)[i] = o;
}

// ---- pass 1a: per-chunk LDS histogram over 128 coarse buckets ----
__global__ __launch_bounds__(256) void part_count_kernel(const int* __restrict__ ei,
        int* __restrict__ gcnt, int* __restrict__ cbase) {
    __shared__ int cnt[NBKT];
    int bx = blockIdx.x;
    int s = bx / NCHK, c = bx - s * NCHK;
    int t = threadIdx.x;
    if (t < NBKT) cnt[t] = 0;
    __syncthreads();
    const int* dstp = ei + (size_t)s * 2 * E_EDGES + E_EDGES;
    int base = c * CHK + t;
    #pragma unroll
    for (int k = 0; k < KPT; ++k) {
        int j = base + k * 256;
        if (j < E_EDGES) atomicAdd(&cnt[dstp[j] / BW_BKT], 1);   // LDS atomic
    }
    __syncthreads();
    if (t < NBKT) {
        int v = cnt[t];
        cbase[(size_t)bx * NBKT + t] = atomicAdd(&gcnt[s * NBKT + t], v);
    }
}

// ---- tiny scan: bucket totals -> global bucket offsets ----
__global__ __launch_bounds__(512) void scan_gcnt_kernel(const int* __restrict__ gcnt,
        int* __restrict__ boffb, int* __restrict__ rowptr4) {
    __shared__ int sh[512];
    int t = threadIdx.x;
    int v = gcnt[t];                           // exactly NPB=512 entries
    sh[t] = v;
    __syncthreads();
    for (int off = 1; off < 512; off <<= 1) {
        int u = (t >= off) ? sh[t - off] : 0;
        __syncthreads();
        sh[t] += u;
        __syncthreads();
    }
    boffb[t] = sh[t] - v;                      // exclusive
    if (t == 0) rowptr4[N4] = E4;
}

// ---- pass 1b: partition edges into bucket-contiguous packed records ----
__global__ __launch_bounds__(256) void part_scatter_kernel(const int* __restrict__ ei,
        const int* __restrict__ boffb, const int* __restrict__ cbase,
        unsigned int* __restrict__ packed) {
    __shared__ int cnt[NBKT];
    __shared__ int sco[NBKT];
    __shared__ int lofs[NBKT + 1];
    __shared__ int cb2[NBKT];
    __shared__ unsigned int lbuf[CHK];         // 16 KB staging
    int bx = blockIdx.x;
    int s = bx / NCHK, c = bx - s * NCHK;
    int t = threadIdx.x;
    if (t < NBKT) cnt[t] = 0;
    __syncthreads();
    const int* srcp = ei + (size_t)s * 2 * E_EDGES;
    const int* dstp = srcp + E_EDGES;
    int base = c * CHK + t;
    unsigned int pv[KPT];
    int prb[KPT];                              // (bucket<<13) | rank  (rank < 4096)
    #pragma unroll
    for (int k = 0; k < KPT; ++k) {
        int j = base + k * 256;
        prb[k] = -1;
        if (j < E_EDGES) {
            int d = dstp[j];
            int b = d / BW_BKT;
            int dl = d - b * BW_BKT;           // < 782 -> 10 bits; src < 2^17
            pv[k] = (unsigned int)srcp[j] | ((unsigned int)dl << 17);
            int r = atomicAdd(&cnt[b], 1);     // LDS atomic
            prb[k] = (b << 13) | r;
        }
    }
    __syncthreads();
    if (t < NBKT) sco[t] = cnt[t];
    __syncthreads();
    for (int off = 1; off < NBKT; off <<= 1) { // exclusive scan over 128 counters
        int u = (t < NBKT && t >= off) ? sco[t - off] : 0;
        __syncthreads();
        if (t < NBKT) sco[t] += u;
        __syncthreads();
    }
    if (t < NBKT) {
        int ex = sco[t] - cnt[t];
        lofs[t] = ex;
        if (t == NBKT - 1) lofs[NBKT] = sco[t];
        cb2[t] = boffb[s * NBKT + t] + cbase[(size_t)bx * NBKT + t] - ex;
    }
    __syncthreads();
    #pragma unroll
    for (int k = 0; k < KPT; ++k) {
        if (prb[k] >= 0) lbuf[lofs[prb[k] >> 13] + (prb[k] & 0x1FFF)] = pv[k];
    }
    __syncthreads();
    int tot = lofs[NBKT];
    for (int i = t; i < tot; i += 256) {       // consecutive i -> coalesced bucket runs
        unsigned int v = lbuf[i];
        int lo = 0, hi = NBKT;
        while (hi - lo > 1) {
            int mid = (lo + hi) >> 1;
            if (lofs[mid] <= i) lo = mid; else hi = mid;
        }
        packed[cb2[lo] + i] = v;
    }
}

// ---- pass 2: per-(snapshot,bucket) CSR build entirely with LDS atomics ----
__global__ __launch_bounds__(1024) void bucket_csr_kernel(const unsigned int* __restrict__ packed,
        const int* __restrict__ gcnt, const int* __restrict__ boffb,
        int* __restrict__ rowptr4, float* __restrict__ dinv4, int* __restrict__ csrsrc4) {
    __shared__ int deg[BW_BKT];                // histogram, then cursor
    __shared__ int sc[1024];
    int bx = blockIdx.x;                       // s*NBKT + b
    int s = bx >> 7, b = bx & (NBKT - 1);
    int t = threadIdx.x;
    int ebase = boffb[bx];
    int ecnt = gcnt[bx];
    for (int i = t; i < BW_BKT; i += 1024) deg[i] = 0;
    __syncthreads();
    const unsigned int* pk = packed + ebase;
    for (int i = t; i < ecnt; i += 1024) atomicAdd(&deg[pk[i] >> 17], 1);  // LDS atomic
    __syncthreads();
    int d0 = (t < BW_BKT) ? deg[t] : 0;
    sc[t] = d0;
    __syncthreads();
    for (int off = 1; off < 1024; off <<= 1) {
        int u = (t >= off) ? sc[t - off] : 0;
        __syncthreads();
        sc[t] += u;
        __syncthreads();
    }
    int ex = sc[t] - d0;                       // exclusive within bucket
    int g = b * BW_BKT + t;
    if (t < BW_BKT && g < N_NODES) {
        rowptr4[s * N_NODES + g] = ebase + ex;
        dinv4[s * N_NODES + g] = rsqrtf((float)(d0 + 1));   // +1 self-loop
    }
    __syncthreads();
    if (t < BW_BKT) deg[t] = ex;               // becomes cursor
    __syncthreads();
    for (int i = t; i < ecnt; i += 1024) {
        unsigned int p = pk[i];
        int r = atomicAdd(&deg[p >> 17], 1);   // LDS atomic, unique slot per dst
        csrsrc4[ebase + r] = (int)(p & 0x1FFFFu);
    }
}

// ------- SpMM layer 0 on RAW features:  agg0 = Ahat_s @ Xbf16   [N,128] bf16 out.
//         (Ahat X) W1 == Ahat (X W1): W1 applied afterwards by gemm_h_mfma.
//         256 B row gathers -> half the bytes of the old xw1 (512 B) gather. -------
__global__ __launch_bounds__(256) void spmm_x_kernel(const unsigned short* __restrict__ xb,
        const float* __restrict__ dinv4, const int* __restrict__ rowptr4,
        const int* __restrict__ csrsrc4, unsigned short* __restrict__ agg0, int soff) {
    int r = (blockIdx.x << 2) + (threadIdx.x >> 6);
    int lane = threadIdx.x & 63;
    int rg = soff + r;
    int e0 = rowptr4[rg], e1 = rowptr4[rg + 1];
    float di = dinv4[rg];
    float accx = 0.f, accy = 0.f;
    const unsigned int* tp = (const unsigned int*)xb;   // 1 uint = 2 bf16; row = 64 uints
    const float* dv = dinv4 + soff;
    int e = e0;
    for (; e + 8 <= e1; e += 8) {                       // 8-deep MLP: 8 x 256B in flight
        int ss[8]; float ww[8]; unsigned int uu[8];
        #pragma unroll
        for (int k = 0; k < 8; ++k) ss[k] = csrsrc4[e + k];
        #pragma unroll
        for (int k = 0; k < 8; ++k) ww[k] = dv[ss[k]] * di;
        #pragma unroll
        for (int k = 0; k < 8; ++k) uu[k] = tp[(size_t)ss[k] * 64 + lane];
        #pragma unroll
        for (int k = 0; k < 8; ++k) {
            accx = fmaf(bf2f((unsigned short)(uu[k] & 0xffffu)), ww[k], accx);
            accy = fmaf(bf2f((unsigned short)(uu[k] >> 16)),     ww[k], accy);
        }
    }
    for (; e < e1; ++e) {
        int s = csrsrc4[e];
        float wv = dv[s] * di;
        unsigned int u = tp[(size_t)s * 64 + lane];
        accx = fmaf(bf2f((unsigned short)(u & 0xffffu)), wv, accx);
        accy = fmaf(bf2f((unsigned short)(u >> 16)),     wv, accy);
    }
    unsigned int us = tp[(size_t)r * 64 + lane];        // self row
    float wd = di * di;
    accx = fmaf(bf2f((unsigned short)(us & 0xffffu)), wd, accx);
    accy = fmaf(bf2f((unsigned short)(us >> 16)),     wd, accy);
    unsigned int o = (unsigned int)f2bf(accx) | ((unsigned int)f2bf(accy) << 16);
    ((unsigned int*)agg0)[(size_t)r * 64 + lane] = o;
}

// ------- MFMA GEMM per snapshot: h = relu(agg0 @ W1 + b1)   [N,256] bf16 -------
// A bf16 [M,128], B fp32 [128,256]. Layouts as gemm_xw1 (HW-verified r8).
__global__ __launch_bounds__(256) void gemm_h_mfma(const unsigned short* __restrict__ A,
        const float* __restrict__ B, const float* __restrict__ b1,
        unsigned short* __restrict__ h, int M) {
    __shared__ unsigned short As[64][136];   // [m][k], +8 pad (row stride 272B, 16B-mult)
    __shared__ unsigned short Bs[64][136];   // [n][k]
    int tid = threadIdx.x;
    int m0 = blockIdx.x * 64, n0 = blockIdx.y * 64;
    {
        int row = tid >> 2, c0 = (tid & 3) * 32;
        int gm = m0 + row;
        #pragma unroll
        for (int i = 0; i < 4; ++i) {
            uint4 v = make_uint4(0u, 0u, 0u, 0u);
            if (gm < M) v = *(const uint4*)(A + (size_t)gm * D_IN + c0 + i * 8);
            *(uint4*)&As[row][c0 + i * 8] = v;
        }
    }
    {
        int k = tid >> 1, nb = (tid & 1) * 32;
        #pragma unroll
        for (int i = 0; i < 8; ++i) {
            float4 v = *(const float4*)(B + (size_t)k * H_DIM + n0 + nb + i * 4);
            Bs[nb + i * 4 + 0][k] = f2bf(v.x);
            Bs[nb + i * 4 + 1][k] = f2bf(v.y);
            Bs[nb + i * 4 + 2][k] = f2bf(v.z);
            Bs[nb + i * 4 + 3][k] = f2bf(v.w);
        }
    }
    __syncthreads();
    int w = tid >> 6, l = tid & 63;
    int q = l >> 4, mrow = l & 15;
    f32x4 acc[4] = {{0.f,0.f,0.f,0.f},{0.f,0.f,0.f,0.f},{0.f,0.f,0.f,0.f},{0.f,0.f,0.f,0.f}};
    #pragma unroll
    for (int kk = 0; kk < 4; ++kk) {
        bf16x8 a = *(const bf16x8*)&As[16 * w + mrow][kk * 32 + q * 8];
        #pragma unroll
        for (int ct = 0; ct < 4; ++ct) {
            bf16x8 b = *(const bf16x8*)&Bs[ct * 16 + mrow][kk * 32 + q * 8];
            acc[ct] = __builtin_amdgcn_mfma_f32_16x16x32_bf16(a, b, acc[ct], 0, 0, 0);
        }
    }
    #pragma unroll
    for (int ct = 0; ct < 4; ++ct) {
        int col = n0 + ct * 16 + mrow;
        float bias = b1[col];
        #pragma unroll
        for (int i = 0; i < 4; ++i) {
            int m = m0 + 16 * w + q * 4 + i;
            if (m < M) h[(size_t)m * H_DIM + col] = f2bf(fmaxf(acc[ct][i] + bias, 0.f));
        }
    }
}

// --- SpMM layer 1 (post rows), accumulating across snapshots ---
__global__ __launch_bounds__(256) void spmm_h_post_kernel(const unsigned short* __restrict__ h,
        const float* __restrict__ dinv4, const int* __restrict__ rowptr4,
        const int* __restrict__ csrsrc4, const int* __restrict__ post,
        float* __restrict__ t1acc, float* __restrict__ hacc, int soff, int first) {
    int p = (blockIdx.x << 2) + (threadIdx.x >> 6);
    int lane = threadIdx.x & 63;
    int r = post[p];
    int rg = soff + r;
    int e0 = rowptr4[rg], e1 = rowptr4[rg + 1];
    float di = dinv4[rg];
    float4 acc = make_float4(0.f, 0.f, 0.f, 0.f);
    const ushort4* hp = (const ushort4*)h;
    const float* dv = dinv4 + soff;
    int e = e0;
    for (; e + 4 <= e1; e += 4) {
        int s0 = csrsrc4[e], s1 = csrsrc4[e + 1], s2 = csrsrc4[e + 2], s3 = csrsrc4[e + 3];
        float w0 = dv[s0] * di, w1 = dv[s1] * di, w2 = dv[s2] * di, w3 = dv[s3] * di;
        ushort4 u0 = hp[(size_t)s0 * 64 + lane];
        ushort4 u1 = hp[(size_t)s1 * 64 + lane];
        ushort4 u2 = hp[(size_t)s2 * 64 + lane];
        ushort4 u3 = hp[(size_t)s3 * 64 + lane];
        acc.x = fmaf(bf2f(u0.x), w0, acc.x); acc.y = fmaf(bf2f(u0.y), w0, acc.y);
        acc.z = fmaf(bf2f(u0.z), w0, acc.z); acc.w = fmaf(bf2f(u0.w), w0, acc.w);
        acc.x = fmaf(bf2f(u1.x), w1, acc.x); acc.y = fmaf(bf2f(u1.y), w1, acc.y);
        acc.z = fmaf(bf2f(u1.z), w1, acc.z); acc.w = fmaf(bf2f(u1.w), w1, acc.w);
        acc.x = fmaf(bf2f(u2.x), w2, acc.x); acc.y = fmaf(bf2f(u2.y), w2, acc.y);
        acc.z = fmaf(bf2f(u2.z), w2, acc.z); acc.w = fmaf(bf2f(u2.w), w2, acc.w);
        acc.x = fmaf(bf2f(u3.x), w3, acc.x); acc.y = fmaf(bf2f(u3.y), w3, acc.y);
        acc.z = fmaf(bf2f(u3.z), w3, acc.z); acc.w = fmaf(bf2f(u3.w), w3, acc.w);
    }
    for (; e < e1; ++e) {
        int s = csrsrc4[e];
        float wv = dv[s] * di;
        ushort4 u = hp[(size_t)s * 64 + lane];
        acc.x = fmaf(bf2f(u.x), wv, acc.x); acc.y = fmaf(bf2f(u.y), wv, acc.y);
        acc.z = fmaf(bf2f(u.z), wv, acc.z); acc.w = fmaf(bf2f(u.w), wv, acc.w);
    }
    ushort4 u = hp[(size_t)r * 64 + lane];        // self row = h_s[post[p]]
    float hx = bf2f(u.x), hy = bf2f(u.y), hz = bf2f(u.z), hw = bf2f(u.w);
    float wd = di * di;
    acc.x = fmaf(hx, wd, acc.x);
    acc.y = fmaf(hy, wd, acc.y);
    acc.z = fmaf(hz, wd, acc.z);
    acc.w = fmaf(hw, wd, acc.w);
    size_t idx = (size_t)p * 64 + lane;
    float4 hv = make_float4(hx, hy, hz, hw);
    if (first) {
        ((float4*)t1acc)[idx] = acc;
        ((float4*)hacc)[idx] = hv;
    } else {
        float4 a = ((float4*)t1acc)[idx];
        a.x += acc.x; a.y += acc.y; a.z += acc.z; a.w += acc.w;
        ((float4*)t1acc)[idx] = a;
        float4 b = ((float4*)hacc)[idx];
        b.x += hv.x; b.y += hv.y; b.z += hv.z; b.w += hv.w;
        ((float4*)hacc)[idx] = b;
    }
}

// ------- MFMA GEMM layer 1 (ONCE): accP = t1acc @ W2 + 4*b2 + hacc -------
__global__ __launch_bounds__(256) void gemm_l1_mfma(const float* __restrict__ A,
        const float* __restrict__ B, const float* __restrict__ b2,
        const float* __restrict__ hacc, float* __restrict__ accP, int M) {
    __shared__ unsigned short As[64][136];
    __shared__ unsigned short Bs[64][136];
    int tid = threadIdx.x;
    int m0 = blockIdx.x * 64, n0 = blockIdx.y * 64;
    int w = tid >> 6, l = tid & 63;
    int q = l >> 4, mrow = l & 15;
    f32x4 acc[4] = {{0.f,0.f,0.f,0.f},{0.f,0.f,0.f,0.f},{0.f,0.f,0.f,0.f},{0.f,0.f,0.f,0.f}};
    for (int kk = 0; kk < 256; kk += 128) {
        __syncthreads();
        {
            int row = tid >> 2, c0 = (tid & 3) * 32;
            int gm = m0 + row;
            #pragma unroll
            for (int i = 0; i < 8; ++i) {
                float4 v = make_float4(0.f, 0.f, 0.f, 0.f);
                if (gm < M) v = *(const float4*)(A + (size_t)gm * 256 + kk + c0 + i * 4);
                As[row][c0 + i * 4 + 0] = f2bf(v.x);
                As[row][c0 + i * 4 + 1] = f2bf(v.y);
                As[row][c0 + i * 4 + 2] = f2bf(v.z);
                As[row][c0 + i * 4 + 3] = f2bf(v.w);
            }
        }
        {
            int k = tid >> 1, nb = (tid & 1) * 32;
            #pragma unroll
            for (int i = 0; i < 8; ++i) {
                float4 v = *(const float4*)(B + (size_t)(kk + k) * H_DIM + n0 + nb + i * 4);
                Bs[nb + i * 4 + 0][k] = f2bf(v.x);
                Bs[nb + i * 4 + 1][k] = f2bf(v.y);
                Bs[nb + i * 4 + 2][k] = f2bf(v.z);
                Bs[nb + i * 4 + 3][k] = f2bf(v.w);
            }
        }
        __syncthreads();
        #pragma unroll
        for (int ks = 0; ks < 4; ++ks) {
            bf16x8 a = *(const bf16x8*)&As[16 * w + mrow][ks * 32 + q * 8];
            #pragma unroll
            for (int ct = 0; ct < 4; ++ct) {
                bf16x8 b = *(const bf16x8*)&Bs[ct * 16 + mrow][ks * 32 + q * 8];
                acc[ct] = __builtin_amdgcn_mfma_f32_16x16x32_bf16(a, b, acc[ct], 0, 0, 0);
            }
        }
    }
    #pragma unroll
    for (int ct = 0; ct < 4; ++ct) {
        int col = n0 + ct * 16 + mrow;
        float bias = 4.0f * b2[col];
        #pragma unroll
        for (int i = 0; i < 4; ++i) {
            int m = m0 + 16 * w + q * 4 + i;
            if (m < M) {
                accP[(size_t)m * 256 + col] =
                    acc[ct][i] + bias + hacc[(size_t)m * 256 + col];
            }
        }
    }
}

// ---------------- classifier ----------------
__global__ __launch_bounds__(128) void classifier_kernel(const float* __restrict__ accP,
        const float* __restrict__ Wc1, const float* __restrict__ bc1,
        const float* __restrict__ Wc2, const float* __restrict__ bc2,
        float* __restrict__ out) {
    __shared__ float arow[8][256];
    __shared__ float red[2][8];
    int p0 = blockIdx.x << 3;
    int tid = threadIdx.x;
    for (int idx = tid; idx < 8 * 256; idx += 128) {
        int pl = idx >> 8, k = idx & 255;
        arow[pl][k] = 0.25f * accP[(size_t)(p0 + pl) * 256 + k];
    }
    __syncthreads();
    float s[8];
    float b = bc1[tid];
    #pragma unroll
    for (int pl = 0; pl < 8; ++pl) s[pl] = b;
    for (int k = 0; k < 256; ++k) {
        float wv = Wc1[k * 128 + tid];
        #pragma unroll
        for (int pl = 0; pl < 8; ++pl) s[pl] = fmaf(arow[pl][k], wv, s[pl]);
    }
    float wc2 = Wc2[tid];
    float part[8];
    #pragma unroll
    for (int pl = 0; pl < 8; ++pl) part[pl] = fmaxf(s[pl], 0.f) * wc2;
    #pragma unroll
    for (int off = 32; off > 0; off >>= 1)
        #pragma unroll
        for (int pl = 0; pl < 8; ++pl) part[pl] += __shfl_down(part[pl], off, 64);
    int wave = tid >> 6, lane = tid & 63;
    if (lane == 0) {
        #pragma unroll
        for (int pl = 0; pl < 8; ++pl) red[wave][pl] = part[pl];
    }
    __syncthreads();
    if (tid < 8) {
        float logit = red[0][tid] + red[1][tid] + bc2[0];
        out[p0 + tid] = 1.f / (1.f + expf(-logit));
    }
}

extern "C" void kernel_launch(void* const* d_in, const int* in_sizes, int n_in,
                              void* d_out, int out_size, void* d_ws, size_t ws_size,
                              hipStream_t stream) {
    const float* x   = (const float*)d_in[0];
    const int*   ei  = (const int*)d_in[1];
    const int*   post= (const int*)d_in[2];
    const float* W1  = (const float*)d_in[3];
    const float* b1  = (const float*)d_in[4];
    const float* W2  = (const float*)d_in[5];
    const float* b2  = (const float*)d_in[6];
    const float* Wc1 = (const float*)d_in[7];
    const float* bc1 = (const float*)d_in[8];
    const float* Wc2 = (const float*)d_in[9];
    const float* bc2 = (const float*)d_in[10];
    float* out = (float*)d_out;

    char* w = (char*)d_ws;
    size_t off = 0;
#define WS_ALLOC(type, name, count) \
    type* name = (type*)(w + off); \
    off += (((size_t)(count) * sizeof(type)) + 255) & ~(size_t)255;
    WS_ALLOC(unsigned short, xb,      (size_t)N_NODES * D_IN)    // 25.6 MB  bf16 X
    WS_ALLOC(unsigned short, agg0,    (size_t)N_NODES * D_IN)    // 25.6 MB  (accP aliases)
    WS_ALLOC(unsigned short, hbuf,    (size_t)N_NODES * H_DIM)   // 51.2 MB  (packed aliases)
    WS_ALLOC(float,          t1acc,   (size_t)P_POST * H_DIM)    // 10.24 MB
    WS_ALLOC(float,          hacc,    (size_t)P_POST * H_DIM)    // 10.24 MB
    WS_ALLOC(float,          dinv4,   N4)                        // 1.6 MB
    WS_ALLOC(int,            rowptr4, N4 + 4)                    // 1.6 MB
    WS_ALLOC(int,            csrsrc4, E4)                        // 25.6 MB
    WS_ALLOC(int,            cbase,   (size_t)S_SNAP * NCHK * NBKT)  // 0.8 MB
    WS_ALLOC(int,            gcnt,    NPB)
    WS_ALLOC(int,            boffb,   NPB)
#undef WS_ALLOC
    // packed[E4] u32 (25.6 MB) aliases hbuf: dead before gemm_h writes h
    // accP [P,256] fp32 (10.24 MB) aliases agg0: agg0 dead after last gemm_h
    unsigned int* packed = (unsigned int*)hbuf;
    float* accP = (float*)agg0;                      // total ws ~152 MB
    (void)ws_size; (void)in_sizes; (void)n_in; (void)out_size;

    // ---- counting-sort graph prep: no per-edge device atomics ----
    zero32_kernel<<<(NPB + 255) / 256, 256, 0, stream>>>((unsigned int*)gcnt, NPB);
    castx_kernel<<<(N_NODES * D_IN / 4) / 256, 256, 0, stream>>>(x, xb);
    part_count_kernel<<<S_SNAP * NCHK, 256, 0, stream>>>(ei, gcnt, cbase);
    scan_gcnt_kernel<<<1, 512, 0, stream>>>(gcnt, boffb, rowptr4);
    part_scatter_kernel<<<S_SNAP * NCHK, 256, 0, stream>>>(ei, boffb, cbase, packed);
    bucket_csr_kernel<<<NPB, 1024, 0, stream>>>(packed, gcnt, boffb, rowptr4, dinv4, csrsrc4);

    dim3 gh((N_NODES + 63) / 64, H_DIM / 64);
    for (int s = 0; s < S_SNAP; ++s) {
        int soff = s * N_NODES;
        // agg0 = Ahat_s @ Xbf16   [N,128]  (256 B row gathers — half the old bytes)
        spmm_x_kernel<<<N_NODES / 4, 256, 0, stream>>>(xb, dinv4, rowptr4, csrsrc4,
                                                       agg0, soff);
        // h = relu(agg0 @ W1 + b1)   [N,256] bf16  (dense MFMA; overwrites packed — dead)
        gemm_h_mfma<<<gh, 256, 0, stream>>>(agg0, W1, b1, hbuf, N_NODES);
        // t1acc (+)= (Ahat @ h)[post];  hacc (+)= h[post]
        spmm_h_post_kernel<<<P_POST / 4, 256, 0, stream>>>(hbuf, dinv4, rowptr4, csrsrc4,
                                                           post, t1acc, hacc, soff, s == 0);
    }
    // accP = t1acc @ W2 + 4*b2 + hacc   — single bf16 MFMA GEMM (W2 snapshot-invariant)
    dim3 g1((P_POST + 63) / 64, H_DIM / 64);
    gemm_l1_mfma<<<g1, 256, 0, stream>>>(t1acc, W2, b2, hacc, accP, P_POST);

    classifier_kernel<<<P_POST / 8, 128, 0, stream>>>(accP, Wc1, bc1, Wc2, bc2, out);
}